// Round 3
// baseline (686.133 us; speedup 1.0000x reference)
//
#include <hip/hip_runtime.h>

typedef unsigned short u16;
typedef unsigned int u32;
typedef __attribute__((ext_vector_type(8))) short short8;
typedef __attribute__((ext_vector_type(4))) float f32x4;
typedef __attribute__((ext_vector_type(4))) u32 u32x4;

__device__ __forceinline__ float bf2f(u16 u){ u32 x = ((u32)u)<<16; float f; __builtin_memcpy(&f,&x,4); return f; }
__device__ __forceinline__ u16 f2bf(float f){ u32 u; __builtin_memcpy(&u,&f,4); u32 r = (u + 0x7fffu + ((u>>16)&1u))>>16; return (u16)r; }

__device__ __forceinline__ float wsum64(float v){
  #pragma unroll
  for (int m=32;m>=1;m>>=1) v += __shfl_xor(v,m,64);
  return v;
}
__device__ __forceinline__ float wsum32(float v){
  #pragma unroll
  for (int m=16;m>=1;m>>=1) v += __shfl_xor(v,m,64);
  return v;
}

// transpose+convert one 128x128 f32 weight: dst[n*128+k] = bf16(src[k*128+n])
__global__ __launch_bounds__(256) void kconv_t(const float* __restrict__ src, u16* __restrict__ dst){
  int t = blockIdx.x*256 + threadIdx.x;
  int n = t>>7, k = t&127;
  dst[n*128+k] = f2bf(src[k*128+n]);
}

// one wave per pair (i,j): dist->rbf->LN->dist_bias; shared edge LN -> zln(bf16) + third -> eb0/ebT
__global__ __launch_bounds__(256) void kprep(
    const float* __restrict__ ee, const float* __restrict__ coords,
    const float* __restrict__ w1, const float* __restrict__ rg, const float* __restrict__ rbta,
    const float* __restrict__ w2, const float* __restrict__ g3, const float* __restrict__ b3,
    const float* __restrict__ w3, const float* __restrict__ gs, const float* __restrict__ bs,
    u16* __restrict__ zln, float* __restrict__ eb0, float* __restrict__ ebT)
{
  int wid = (blockIdx.x*256 + threadIdx.x)>>6;
  int lane = threadIdx.x & 63;
  int i = wid>>8, j = wid&255;
  float dx = coords[i*3+0]-coords[j*3+0];
  float dy = coords[i*3+1]-coords[j*3+1];
  float dz = coords[i*3+2]-coords[j*3+2];
  float dist = sqrtf(dx*dx+dy*dy+dz*dz+1e-12f);
  float rbv = 0.f;
  if (lane<39){ float t = (dist-(0.325f+0.125f*(float)lane))*8.210526315789474f; rbv = __expf(-t*t); }
  int c = lane&31;
  float hacc = 0.f;
  #pragma unroll
  for (int r=0;r<39;r++){ float rv = __shfl(rbv,r,64); hacc = fmaf(rv, w1[r*32+c], hacc); }
  float mu = wsum32(hacc)*(1.f/32.f);
  float vr = wsum32(hacc*hacc)*(1.f/32.f) - mu*mu;
  float hn = (hacc-mu)*rsqrtf(vr+1e-5f)*rg[c]+rbta[c];
  float db0 = wsum32(hn*w2[c*4+0]);
  float db1 = wsum32(hn*w2[c*4+1]);
  float db2 = wsum32(hn*w2[c*4+2]);
  float db3 = wsum32(hn*w2[c*4+3]);
  int c0 = lane*2, c1 = lane*2+1;
  float x0 = ee[(size_t)wid*128+c0], x1 = ee[(size_t)wid*128+c1];
  float m2 = wsum64(x0+x1)*(1.f/128.f);
  float v2 = wsum64(x0*x0+x1*x1)*(1.f/128.f)-m2*m2;
  float rinv = rsqrtf(v2+1e-5f);
  float n0 = (x0-m2)*rinv, n1 = (x1-m2)*rinv;
  u32 pk = (u32)f2bf(n0*gs[c0]+bs[c0]) | ((u32)f2bf(n1*gs[c1]+bs[c1])<<16);
  ((u32*)zln)[(size_t)wid*64+lane] = pk;
  float t0 = n0*g3[c0]+b3[c0], t1 = n1*g3[c1]+b3[c1];
  float th0 = wsum64(t0*w3[c0*4+0]+t1*w3[c1*4+0]);
  float th1 = wsum64(t0*w3[c0*4+1]+t1*w3[c1*4+1]);
  float th2 = wsum64(t0*w3[c0*4+2]+t1*w3[c1*4+2]);
  float th3 = wsum64(t0*w3[c0*4+3]+t1*w3[c1*4+3]);
  if (lane<4){
    float v = (lane==0)?(db0+th0):(lane==1)?(db1+th1):(lane==2)?(db2+th2):(db3+th3);
    eb0[((size_t)lane*256+i)*256 + j] = v;   // [h][q=i][k=j]
    ebT[((size_t)lane*256+j)*256 + i] = v;   // [h][q=j][k=i] (transposed frame)
  }
}

// LN of z1 with e-params, written transposed: zln[j*256+i] = LN(z1[i*256+j])
__global__ __launch_bounds__(256) void klnt(const float* __restrict__ z1, const float* __restrict__ g,
                                            const float* __restrict__ b, u16* __restrict__ zln){
  int wid = (blockIdx.x*256+threadIdx.x)>>6;
  int lane = threadIdx.x&63;
  int a = wid>>8, bb = wid&255;
  int c0 = lane*2, c1 = c0+1;
  float x0 = z1[(size_t)wid*128+c0], x1 = z1[(size_t)wid*128+c1];
  float m = wsum64(x0+x1)*(1.f/128.f);
  float v = wsum64(x0*x0+x1*x1)*(1.f/128.f)-m*m;
  float rinv = rsqrtf(v+1e-5f);
  u32 pk = (u32)f2bf((x0-m)*rinv*g[c0]+b[c0]) | ((u32)f2bf((x1-m)*rinv*g[c1]+b[c1])<<16);
  ((u32*)zln)[((size_t)bb*256+a)*64+lane] = pk;
}

// zln[65536,128] @ wT[sel] ; sel0->Qf frag-tiled, sel1->Kf frag-tiled, sel2->Vf frag-tiled, sel3->G row-major sigmoid
__global__ __launch_bounds__(256) void kqkvg(const u16* __restrict__ zln, const u16* __restrict__ wT,
                                             u16* __restrict__ Qf, u16* __restrict__ Kf,
                                             u16* __restrict__ Vf, u16* __restrict__ Gm){
  const int m0 = blockIdx.x*128;
  const int sel = blockIdx.y;
  __shared__ u16 A[128*136];
  const int tid = threadIdx.x;
  #pragma unroll
  for (int r=0;r<8;r++){
    int chunk = tid + 256*r;
    int row = chunk>>4, off = (chunk&15)*8;
    *(u32x4*)&A[row*136+off] = *(const u32x4*)&zln[(size_t)(m0+row)*128+off];
  }
  __syncthreads();
  const int w = tid>>6, lane = tid&63, r16 = lane&15, gq = lane>>4;
  short8 a[2][4];
  #pragma unroll
  for (int mt=0;mt<2;mt++)
    #pragma unroll
    for (int ks=0;ks<4;ks++)
      a[mt][ks] = *(const short8*)&A[(w*32+mt*16+r16)*136 + ks*32 + gq*8];
  f32x4 acc[2][8];
  #pragma unroll
  for (int mt=0;mt<2;mt++)
    #pragma unroll
    for (int nt=0;nt<8;nt++)
      acc[mt][nt] = (f32x4){0.f,0.f,0.f,0.f};
  #pragma unroll
  for (int nt=0;nt<8;nt++){
    short8 bq[4];
    #pragma unroll
    for (int ks=0;ks<4;ks++)
      bq[ks] = *(const short8*)&wT[(size_t)(sel*128+nt*16+r16)*128 + ks*32 + gq*8];
    #pragma unroll
    for (int mt=0;mt<2;mt++)
      #pragma unroll
      for (int ks=0;ks<4;ks++)
        acc[mt][nt] = __builtin_amdgcn_mfma_f32_16x16x32_bf16(a[mt][ks], bq[ks], acc[mt][nt], 0,0,0);
  }
  #pragma unroll
  for (int mt=0;mt<2;mt++){
    int mbase = m0 + w*32 + mt*16 + gq*4;
    #pragma unroll
    for (int nt=0;nt<8;nt++){
      int n = nt*16+r16;
      #pragma unroll
      for (int reg=0;reg<4;reg++){
        int m = mbase+reg;
        float v = acc[mt][nt][reg];
        if (sel==3){
          v = 1.f/(1.f+__expf(-v));
          Gm[(size_t)m*128+n] = f2bf(v);
        } else if (sel==2){
          int j=m&255, ii=m>>8, hh=n>>5, c=n&31;
          size_t idx = ((((size_t)(ii*4+hh)*8 + (j>>5))*2 + ((c>>4)&1))*64
                        + (((j>>3)&3)*16 + (c&15)))*8 + (j&7);
          Vf[idx]=f2bf(v);
        } else {
          int ii=m>>8, qrow=m&255, hh=n>>5, c=n&31;
          size_t idx = (((size_t)(ii*4+hh)*16 + (qrow>>4))*64
                        + (((c>>3)&3)*16 + (qrow&15)))*8 + (c&7);
          if (sel==0) Qf[idx]=f2bf(v); else Kf[idx]=f2bf(v);
        }
      }
    }
  }
}

// attention: frag-coalesced loads, two-half exp (no max), normalize in epilogue
__global__ __launch_bounds__(256,4) void kattn(const u16* __restrict__ Qf, const u16* __restrict__ Kf,
                                               const u16* __restrict__ Vf, const float* __restrict__ eb,
                                               const float* __restrict__ mask, u16* __restrict__ og,
                                               const int epass){
  const int i = blockIdx.x, qc = blockIdx.y, tid = threadIdx.x;
  const int h = tid>>6, lane = tid&63, r16 = lane&15, gq = lane>>4;
  __shared__ u16 P[4][16*264];
  u16* Ph = P[h];
  float mb[16];
  #pragma unroll
  for (int kt=0;kt<16;kt++){
    int k = kt*16+r16;
    mb[kt] = (mask[epass ? k*256+i : i*256+k]-1.f)*1e8f;
  }
  const u16* qhb = Qf + (size_t)(i*4+h)*16*512;
  const u16* khb = Kf + (size_t)(i*4+h)*16*512;
  const u16* vhb = Vf + (size_t)(i*4+h)*16*512;
  const float* ebh = eb + (size_t)h*256*256;
  for (int qt=qc*4; qt<qc*4+4; qt++){
    short8 aq = *(const short8*)&qhb[qt*512 + lane*8];
    float sums[4] = {0.f,0.f,0.f,0.f};
    #pragma unroll
    for (int half=0;half<2;half++){
      f32x4 s[8];
      #pragma unroll
      for (int kt2=0;kt2<8;kt2++){
        short8 bk = *(const short8*)&khb[(half*8+kt2)*512 + lane*8];
        f32x4 z = {0.f,0.f,0.f,0.f};
        s[kt2] = __builtin_amdgcn_mfma_f32_16x16x32_bf16(aq, bk, z, 0,0,0);
      }
      #pragma unroll
      for (int kt2=0;kt2<8;kt2++){
        int kk = half*128 + kt2*16 + r16;
        #pragma unroll
        for (int reg=0;reg<4;reg++){
          int q = qt*16+gq*4+reg;
          float bias = ebh[(size_t)q*256 + kk] + mb[half*8+kt2];
          float e = __expf(fmaf(s[kt2][reg], 0.17677669529663687f, bias));
          sums[reg] += e;
          Ph[(gq*4+reg)*264 + kk] = f2bf(e);
        }
      }
    }
    #pragma unroll
    for (int reg=0;reg<4;reg++){
      #pragma unroll
      for (int mm=1;mm<=8;mm<<=1) sums[reg] += __shfl_xor(sums[reg],mm,64);
      sums[reg] = 1.f/sums[reg];
    }
    f32x4 o[2]; o[0]=(f32x4){0.f,0.f,0.f,0.f}; o[1]=(f32x4){0.f,0.f,0.f,0.f};
    #pragma unroll
    for (int ks=0;ks<8;ks++){
      short8 ap = *(const short8*)&Ph[r16*264 + ks*32 + gq*8];
      #pragma unroll
      for (int ct=0;ct<2;ct++){
        short8 bv = *(const short8*)&vhb[(ks*2+ct)*512 + lane*8];
        o[ct] = __builtin_amdgcn_mfma_f32_16x16x32_bf16(ap, bv, o[ct], 0,0,0);
      }
    }
    #pragma unroll
    for (int ct=0;ct<2;ct++)
      #pragma unroll
      for (int reg=0;reg<4;reg++){
        int q = qt*16+gq*4+reg, cc = ct*16+r16;
        og[((size_t)i*256+q)*128 + h*32 + cc] = f2bf(o[ct][reg]*sums[reg]);
      }
  }
}

// (og*G)[65536,128] @ woT + residual -> out (epass: transposed scatter back)
__global__ __launch_bounds__(256) void kproj(const u16* __restrict__ og, const u16* __restrict__ Gm,
                                             const u16* __restrict__ woT,
                                             const float* __restrict__ resid, float* __restrict__ out,
                                             const int epass){
  const int m0 = blockIdx.x*128;
  __shared__ u16 A[128*136];
  const int tid = threadIdx.x;
  #pragma unroll
  for (int r=0;r<8;r++){
    int chunk = tid + 256*r;
    int row = chunk>>4, off = (chunk&15)*8;
    short8 av = *(const short8*)&og[(size_t)(m0+row)*128+off];
    short8 gv = *(const short8*)&Gm[(size_t)(m0+row)*128+off];
    u16 tmp[8];
    #pragma unroll
    for (int e=0;e<8;e++) tmp[e] = f2bf(bf2f((u16)av[e])*bf2f((u16)gv[e]));
    u32x4 packed; __builtin_memcpy(&packed, tmp, 16);
    *(u32x4*)&A[row*136+off] = packed;
  }
  __syncthreads();
  const int w = tid>>6, lane = tid&63, r16 = lane&15, gq = lane>>4;
  short8 a[2][4];
  #pragma unroll
  for (int mt=0;mt<2;mt++)
    #pragma unroll
    for (int ks=0;ks<4;ks++)
      a[mt][ks] = *(const short8*)&A[(w*32+mt*16+r16)*136 + ks*32 + gq*8];
  f32x4 acc[2][8];
  #pragma unroll
  for (int mt=0;mt<2;mt++)
    #pragma unroll
    for (int nt=0;nt<8;nt++)
      acc[mt][nt] = (f32x4){0.f,0.f,0.f,0.f};
  #pragma unroll
  for (int nt=0;nt<8;nt++){
    short8 bq[4];
    #pragma unroll
    for (int ks=0;ks<4;ks++)
      bq[ks] = *(const short8*)&woT[(size_t)(nt*16+r16)*128 + ks*32 + gq*8];
    #pragma unroll
    for (int mt=0;mt<2;mt++)
      #pragma unroll
      for (int ks=0;ks<4;ks++)
        acc[mt][nt] = __builtin_amdgcn_mfma_f32_16x16x32_bf16(a[mt][ks], bq[ks], acc[mt][nt], 0,0,0);
  }
  #pragma unroll
  for (int mt=0;mt<2;mt++){
    int mbase = m0+w*32+mt*16+gq*4;
    #pragma unroll
    for (int nt=0;nt<8;nt++){
      int n = nt*16+r16;
      #pragma unroll
      for (int reg=0;reg<4;reg++){
        int m = mbase+reg;
        size_t idx = epass ? ((size_t)((m&255)*256+(m>>8)))*128+(size_t)n : (size_t)m*128+(size_t)n;
        out[idx] = resid[idx] + acc[mt][nt][reg];
      }
    }
  }
}

extern "C" void kernel_launch(void* const* d_in, const int* in_sizes, int n_in,
                              void* d_out, int out_size, void* d_ws, size_t ws_size,
                              hipStream_t stream) {
  const float* ee     = (const float*)d_in[0];
  const float* coords = (const float*)d_in[1];
  const float* mask   = (const float*)d_in[2];
  const float* w1     = (const float*)d_in[3];
  const float* rg     = (const float*)d_in[4];
  const float* rbta   = (const float*)d_in[5];
  const float* w2     = (const float*)d_in[6];
  const float* g3     = (const float*)d_in[7];
  const float* b3     = (const float*)d_in[8];
  const float* w3     = (const float*)d_in[9];
  const float* sln_g  = (const float*)d_in[10];
  const float* sln_b  = (const float*)d_in[11];
  const float* eln_g  = (const float*)d_in[17];
  const float* eln_b  = (const float*)d_in[18];
  float* out = (float*)d_out;
  char* ws = (char*)d_ws;

  u16*   wT_s  = (u16*)(ws + 0);           // 512x128 bf16
  u16*   wT_e  = (u16*)(ws + 131072);
  u16*   woT_s = (u16*)(ws + 262144);      // 128x128 bf16
  u16*   woT_e = (u16*)(ws + 294912);
  float* eb0   = (float*)(ws + 327680);    // [4][256][256] f32
  float* ebT   = (float*)(ws + 1376256);   // [4][256][256] f32
  u16*   zln   = (u16*)(ws + 2424832);     // [65536][128] bf16 (reused as og)
  u16*   Qf    = (u16*)(ws + 19202048);    // frag-tiled [256*4*16][512]
  u16*   Kf    = (u16*)(ws + 35979264);
  u16*   Vf    = (u16*)(ws + 52756480);
  u16*   Gm    = (u16*)(ws + 69533696);    // [65536][128] bf16

  for (int s=0;s<4;s++)
    kconv_t<<<64,256,0,stream>>>((const float*)d_in[12+s], wT_s + s*128*128);
  kconv_t<<<64,256,0,stream>>>((const float*)d_in[16], woT_s);
  for (int s=0;s<4;s++)
    kconv_t<<<64,256,0,stream>>>((const float*)d_in[19+s], wT_e + s*128*128);
  kconv_t<<<64,256,0,stream>>>((const float*)d_in[23], woT_e);

  kprep<<<16384,256,0,stream>>>(ee, coords, w1, rg, rbta, w2, g3, b3, w3, sln_g, sln_b, zln, eb0, ebT);

  // ---- starting pass ----
  kqkvg<<<dim3(512,4),256,0,stream>>>(zln, wT_s, Qf, Kf, Vf, Gm);
  kattn<<<dim3(256,4),256,0,stream>>>(Qf, Kf, Vf, eb0, mask, zln /*og*/, 0);
  kproj<<<512,256,0,stream>>>(zln /*og*/, Gm, woT_s, ee, out, 0);

  // ---- ending pass (transposed frame) ----
  klnt<<<16384,256,0,stream>>>(out, eln_g, eln_b, zln);
  kqkvg<<<dim3(512,4),256,0,stream>>>(zln, wT_e, Qf, Kf, Vf, Gm);
  kattn<<<dim3(256,4),256,0,stream>>>(Qf, Kf, Vf, ebT, mask, zln /*og*/, 1);
  kproj<<<512,256,0,stream>>>(zln /*og*/, Gm, woT_e, out, out, 1);
}

// Round 4
// 544.543 us; speedup vs baseline: 1.2600x; 1.2600x over previous
//
#include <hip/hip_runtime.h>

typedef unsigned short u16;
typedef unsigned int u32;
typedef __attribute__((ext_vector_type(8))) short short8;
typedef __attribute__((ext_vector_type(4))) float f32x4;
typedef __attribute__((ext_vector_type(4))) u32 u32x4;

__device__ __forceinline__ float bf2f(u16 u){ u32 x = ((u32)u)<<16; float f; __builtin_memcpy(&f,&x,4); return f; }
__device__ __forceinline__ u16 f2bf(float f){ u32 u; __builtin_memcpy(&u,&f,4); u32 r = (u + 0x7fffu + ((u>>16)&1u))>>16; return (u16)r; }

__device__ __forceinline__ float wsum64(float v){
  #pragma unroll
  for (int m=32;m>=1;m>>=1) v += __shfl_xor(v,m,64);
  return v;
}
__device__ __forceinline__ float wsum32(float v){
  #pragma unroll
  for (int m=16;m>=1;m>>=1) v += __shfl_xor(v,m,64);
  return v;
}

// transpose+convert one 128x128 f32 weight: dst[n*128+k] = bf16(src[k*128+n])
__global__ __launch_bounds__(256) void kconv_t(const float* __restrict__ src, u16* __restrict__ dst){
  int t = blockIdx.x*256 + threadIdx.x;
  int n = t>>7, k = t&127;
  dst[n*128+k] = f2bf(src[k*128+n]);
}

// one wave per pair (i,j): dist->rbf->LN->dist_bias; shared edge LN -> zln + exp(bias) in C-frag layout
__global__ __launch_bounds__(256) void kprep(
    const float* __restrict__ ee, const float* __restrict__ coords,
    const float* __restrict__ w1, const float* __restrict__ rg, const float* __restrict__ rbta,
    const float* __restrict__ w2, const float* __restrict__ g3, const float* __restrict__ b3,
    const float* __restrict__ w3, const float* __restrict__ gs, const float* __restrict__ bs,
    const float* __restrict__ mask,
    u16* __restrict__ zln, u16* __restrict__ ebx0, u16* __restrict__ ebxT,
    float* __restrict__ maskE)
{
  int wid = (blockIdx.x*256 + threadIdx.x)>>6;
  int lane = threadIdx.x & 63;
  int i = wid>>8, j = wid&255;
  float dx = coords[i*3+0]-coords[j*3+0];
  float dy = coords[i*3+1]-coords[j*3+1];
  float dz = coords[i*3+2]-coords[j*3+2];
  float dist = sqrtf(dx*dx+dy*dy+dz*dz+1e-12f);
  float rbv = 0.f;
  if (lane<39){ float t = (dist-(0.325f+0.125f*(float)lane))*8.210526315789474f; rbv = __expf(-t*t); }
  int c = lane&31;
  float hacc = 0.f;
  #pragma unroll
  for (int r=0;r<39;r++){ float rv = __shfl(rbv,r,64); hacc = fmaf(rv, w1[r*32+c], hacc); }
  float mu = wsum32(hacc)*(1.f/32.f);
  float vr = wsum32(hacc*hacc)*(1.f/32.f) - mu*mu;
  float hn = (hacc-mu)*rsqrtf(vr+1e-5f)*rg[c]+rbta[c];
  float db0 = wsum32(hn*w2[c*4+0]);
  float db1 = wsum32(hn*w2[c*4+1]);
  float db2 = wsum32(hn*w2[c*4+2]);
  float db3 = wsum32(hn*w2[c*4+3]);
  int c0 = lane*2, c1 = lane*2+1;
  float x0 = ee[(size_t)wid*128+c0], x1 = ee[(size_t)wid*128+c1];
  float m2 = wsum64(x0+x1)*(1.f/128.f);
  float v2 = wsum64(x0*x0+x1*x1)*(1.f/128.f)-m2*m2;
  float rinv = rsqrtf(v2+1e-5f);
  float n0 = (x0-m2)*rinv, n1 = (x1-m2)*rinv;
  u32 pk = (u32)f2bf(n0*gs[c0]+bs[c0]) | ((u32)f2bf(n1*gs[c1]+bs[c1])<<16);
  ((u32*)zln)[(size_t)wid*64+lane] = pk;
  float t0 = n0*g3[c0]+b3[c0], t1 = n1*g3[c1]+b3[c1];
  float th0 = wsum64(t0*w3[c0*4+0]+t1*w3[c1*4+0]);
  float th1 = wsum64(t0*w3[c0*4+1]+t1*w3[c1*4+1]);
  float th2 = wsum64(t0*w3[c0*4+2]+t1*w3[c1*4+2]);
  float th3 = wsum64(t0*w3[c0*4+3]+t1*w3[c1*4+3]);
  if (lane<4){
    float v = (lane==0)?(db0+th0):(lane==1)?(db1+th1):(lane==2)?(db2+th2):(db3+th3);
    u16 ev = f2bf(__expf(v));
    int h = lane;
    // pass0: q=i,k=j  -> tile(h, i>>4, j>>4), lane (j&15)+((i>>2)&3)*16, reg i&3
    ebx0[(((size_t)(h*16+(i>>4))*16+(j>>4))*256) + ((j&15)+((i>>2)&3)*16)*4 + (i&3)] = ev;
    // passT: q=j,k=i
    ebxT[(((size_t)(h*16+(j>>4))*16+(i>>4))*256) + ((i&15)+((j>>2)&3)*16)*4 + (j&3)] = ev;
  }
  if (lane==4) maskE[(size_t)j*256+i] = mask[(size_t)wid];
}

// LN of z1 with e-params, written transposed: zln[j*256+i] = LN(z1[i*256+j])
__global__ __launch_bounds__(256) void klnt(const float* __restrict__ z1, const float* __restrict__ g,
                                            const float* __restrict__ b, u16* __restrict__ zln){
  int wid = (blockIdx.x*256+threadIdx.x)>>6;
  int lane = threadIdx.x&63;
  int a = wid>>8, bb = wid&255;
  int c0 = lane*2, c1 = c0+1;
  float x0 = z1[(size_t)wid*128+c0], x1 = z1[(size_t)wid*128+c1];
  float m = wsum64(x0+x1)*(1.f/128.f);
  float v = wsum64(x0*x0+x1*x1)*(1.f/128.f)-m*m;
  float rinv = rsqrtf(v+1e-5f);
  u32 pk = (u32)f2bf((x0-m)*rinv*g[c0]+b[c0]) | ((u32)f2bf((x1-m)*rinv*g[c1]+b[c1])<<16);
  ((u32*)zln)[((size_t)bb*256+a)*64+lane] = pk;
}

// zln[65536,128] @ wT[sel]; outputs restaged via LDS -> all global stores 16B coalesced.
// sel0->Qf (A-frag), sel1->Kf (A-frag), sel2->Vf (B-frag, transposed restage), sel3->Gm row-major sigmoid
__global__ __launch_bounds__(256) void kqkvg(const u16* __restrict__ zln, const u16* __restrict__ wT,
                                             u16* __restrict__ Qf, u16* __restrict__ Kf,
                                             u16* __restrict__ Vf, u16* __restrict__ Gm){
  const int m0 = blockIdx.x*128;
  const int sel = blockIdx.y;
  __shared__ u16 A[128*136];
  const int tid = threadIdx.x;
  #pragma unroll
  for (int r=0;r<8;r++){
    int chunk = tid + 256*r;
    int row = chunk>>4, off = (chunk&15)*8;
    *(u32x4*)&A[row*136+off] = *(const u32x4*)&zln[(size_t)(m0+row)*128+off];
  }
  __syncthreads();
  const int w = tid>>6, lane = tid&63, r16 = lane&15, gq = lane>>4;
  short8 a[2][4];
  #pragma unroll
  for (int mt=0;mt<2;mt++)
    #pragma unroll
    for (int ks=0;ks<4;ks++)
      a[mt][ks] = *(const short8*)&A[(w*32+mt*16+r16)*136 + ks*32 + gq*8];
  f32x4 acc[2][8];
  #pragma unroll
  for (int mt=0;mt<2;mt++)
    #pragma unroll
    for (int nt=0;nt<8;nt++)
      acc[mt][nt] = (f32x4){0.f,0.f,0.f,0.f};
  #pragma unroll
  for (int nt=0;nt<8;nt++){
    short8 bq[4];
    #pragma unroll
    for (int ks=0;ks<4;ks++)
      bq[ks] = *(const short8*)&wT[(size_t)(sel*128+nt*16+r16)*128 + ks*32 + gq*8];
    #pragma unroll
    for (int mt=0;mt<2;mt++)
      #pragma unroll
      for (int ks=0;ks<4;ks++)
        acc[mt][nt] = __builtin_amdgcn_mfma_f32_16x16x32_bf16(a[mt][ks], bq[ks], acc[mt][nt], 0,0,0);
  }
  __syncthreads();   // everyone done reading A
  if (sel==2){
    // transposed restage: A[col][row]
    #pragma unroll
    for (int mt=0;mt<2;mt++)
      #pragma unroll
      for (int nt=0;nt<8;nt++)
        #pragma unroll
        for (int reg=0;reg<4;reg++)
          A[(nt*16+r16)*136 + (w*32+mt*16+gq*4+reg)] = f2bf(acc[mt][nt][reg]);
  } else {
    #pragma unroll
    for (int mt=0;mt<2;mt++)
      #pragma unroll
      for (int nt=0;nt<8;nt++)
        #pragma unroll
        for (int reg=0;reg<4;reg++){
          float v = acc[mt][nt][reg];
          if (sel==3) v = 1.f/(1.f+__expf(-v));
          A[(w*32+mt*16+gq*4+reg)*136 + nt*16+r16] = f2bf(v);
        }
  }
  __syncthreads();
  const int ii = m0>>8, hb = (blockIdx.x&1);
  if (sel==3){
    #pragma unroll
    for (int it=0; it<8; it++){
      int slot = it*256+tid; int row = slot>>4, c8 = (slot&15)*8;
      u32x4 vdat = *(const u32x4*)&A[row*136 + c8];
      *(u32x4*)&Gm[(size_t)(m0+row)*128 + c8] = vdat;
    }
  } else if (sel==2){
    #pragma unroll
    for (int it=0; it<8; it++){
      int slot = it*256+tid; int tile = slot>>6, l = slot&63;
      int hh = tile>>3, j32l = (tile>>1)&3, c16 = tile&1;
      u32x4 vdat = *(const u32x4*)&A[(hh*32 + c16*16 + (l&15))*136 + j32l*32 + (l>>4)*8];
      size_t gidx = ((((size_t)(ii*4+hh)*8 + hb*4 + j32l)*2 + c16)*64 + l)*8;
      *(u32x4*)&Vf[gidx] = vdat;
    }
  } else {
    u16* __restrict__ dst = (sel==0)? Qf : Kf;
    #pragma unroll
    for (int it=0; it<8; it++){
      int slot = it*256+tid; int tile = slot>>6, l = slot&63;
      int a8 = tile>>2, hh = tile&3;
      u32x4 vdat = *(const u32x4*)&A[(a8*16 + (l&15))*136 + hh*32 + (l>>4)*8];
      size_t gidx = (((size_t)(ii*4+hh)*16 + hb*8 + a8)*64 + l)*8;
      *(u32x4*)&dst[gidx] = vdat;
    }
  }
}

// attention: all-coalesced loads; P = exp(s*scale)*expbias(bf16 frag)*mask; normalize in epilogue
__global__ __launch_bounds__(256,4) void kattn(const u16* __restrict__ Qf, const u16* __restrict__ Kf,
                                               const u16* __restrict__ Vf, const u16* __restrict__ ebx,
                                               const float* __restrict__ maskp, u16* __restrict__ og){
  const int i = blockIdx.x, qc = blockIdx.y, tid = threadIdx.x;
  const int h = tid>>6, lane = tid&63, r16 = lane&15, gq = lane>>4;
  __shared__ u16 P[4][16*264];
  u16* Ph = P[h];
  float pm[16];
  const float* mrow = maskp + (size_t)i*256;
  #pragma unroll
  for (int kt=0;kt<16;kt++){
    float mv = mrow[kt*16+r16];
    pm[kt] = (mv > 0.999f) ? 1.f : 0.f;
  }
  const u16* qhb = Qf + (size_t)(i*4+h)*16*512;
  const u16* khb = Kf + (size_t)(i*4+h)*16*512;
  const u16* vhb = Vf + (size_t)(i*4+h)*16*512;
  const u16* ebt = ebx + (size_t)h*16*16*256;
  for (int qt=qc*4; qt<qc*4+4; qt++){
    short8 aq = *(const short8*)&qhb[qt*512 + lane*8];
    float sums[4] = {0.f,0.f,0.f,0.f};
    #pragma unroll
    for (int half=0;half<2;half++){
      f32x4 s[8];
      #pragma unroll
      for (int kt2=0;kt2<8;kt2++){
        short8 bk = *(const short8*)&khb[(half*8+kt2)*512 + lane*8];
        f32x4 z = {0.f,0.f,0.f,0.f};
        s[kt2] = __builtin_amdgcn_mfma_f32_16x16x32_bf16(aq, bk, z, 0,0,0);
      }
      #pragma unroll
      for (int kt2=0;kt2<8;kt2++){
        int kt = half*8+kt2;
        int kk = kt*16 + r16;
        uint2 er = *(const uint2*)&ebt[((size_t)(qt*16+kt)*64 + lane)*4];
        u16 e4[4]; __builtin_memcpy(e4, &er, 8);
        #pragma unroll
        for (int reg=0;reg<4;reg++){
          float e = __expf(s[kt2][reg]*0.17677669529663687f) * bf2f(e4[reg]) * pm[kt];
          sums[reg] += e;
          Ph[(gq*4+reg)*264 + kk] = f2bf(e);
        }
      }
    }
    #pragma unroll
    for (int reg=0;reg<4;reg++){
      #pragma unroll
      for (int mm=1;mm<=8;mm<<=1) sums[reg] += __shfl_xor(sums[reg],mm,64);
      sums[reg] = 1.f/sums[reg];
    }
    f32x4 o[2]; o[0]=(f32x4){0.f,0.f,0.f,0.f}; o[1]=(f32x4){0.f,0.f,0.f,0.f};
    #pragma unroll
    for (int ks=0;ks<8;ks++){
      short8 ap = *(const short8*)&Ph[r16*264 + ks*32 + gq*8];
      #pragma unroll
      for (int ct=0;ct<2;ct++){
        short8 bv = *(const short8*)&vhb[(ks*2+ct)*512 + lane*8];
        o[ct] = __builtin_amdgcn_mfma_f32_16x16x32_bf16(ap, bv, o[ct], 0,0,0);
      }
    }
    #pragma unroll
    for (int ct=0;ct<2;ct++)
      #pragma unroll
      for (int reg=0;reg<4;reg++){
        int q = qt*16+gq*4+reg, cc = ct*16+r16;
        og[((size_t)i*256+q)*128 + h*32 + cc] = f2bf(o[ct][reg]*sums[reg]);
      }
  }
}

// (og*G)[65536,128] @ woT + residual -> out (epass: transposed scatter back)
__global__ __launch_bounds__(256) void kproj(const u16* __restrict__ og, const u16* __restrict__ Gm,
                                             const u16* __restrict__ woT,
                                             const float* __restrict__ resid, float* __restrict__ out,
                                             const int epass){
  const int m0 = blockIdx.x*128;
  __shared__ u16 A[128*136];
  const int tid = threadIdx.x;
  #pragma unroll
  for (int r=0;r<8;r++){
    int chunk = tid + 256*r;
    int row = chunk>>4, off = (chunk&15)*8;
    short8 av = *(const short8*)&og[(size_t)(m0+row)*128+off];
    short8 gv = *(const short8*)&Gm[(size_t)(m0+row)*128+off];
    u16 tmp[8];
    #pragma unroll
    for (int e=0;e<8;e++) tmp[e] = f2bf(bf2f((u16)av[e])*bf2f((u16)gv[e]));
    u32x4 packed; __builtin_memcpy(&packed, tmp, 16);
    *(u32x4*)&A[row*136+off] = packed;
  }
  __syncthreads();
  const int w = tid>>6, lane = tid&63, r16 = lane&15, gq = lane>>4;
  short8 a[2][4];
  #pragma unroll
  for (int mt=0;mt<2;mt++)
    #pragma unroll
    for (int ks=0;ks<4;ks++)
      a[mt][ks] = *(const short8*)&A[(w*32+mt*16+r16)*136 + ks*32 + gq*8];
  f32x4 acc[2][8];
  #pragma unroll
  for (int mt=0;mt<2;mt++)
    #pragma unroll
    for (int nt=0;nt<8;nt++)
      acc[mt][nt] = (f32x4){0.f,0.f,0.f,0.f};
  #pragma unroll
  for (int nt=0;nt<8;nt++){
    short8 bq[4];
    #pragma unroll
    for (int ks=0;ks<4;ks++)
      bq[ks] = *(const short8*)&woT[(size_t)(nt*16+r16)*128 + ks*32 + gq*8];
    #pragma unroll
    for (int mt=0;mt<2;mt++)
      #pragma unroll
      for (int ks=0;ks<4;ks++)
        acc[mt][nt] = __builtin_amdgcn_mfma_f32_16x16x32_bf16(a[mt][ks], bq[ks], acc[mt][nt], 0,0,0);
  }
  #pragma unroll
  for (int mt=0;mt<2;mt++){
    int mbase = m0+w*32+mt*16+gq*4;
    #pragma unroll
    for (int nt=0;nt<8;nt++){
      int n = nt*16+r16;
      #pragma unroll
      for (int reg=0;reg<4;reg++){
        int m = mbase+reg;
        size_t idx = epass ? ((size_t)((m&255)*256+(m>>8)))*128+(size_t)n : (size_t)m*128+(size_t)n;
        out[idx] = resid[idx] + acc[mt][nt][reg];
      }
    }
  }
}

extern "C" void kernel_launch(void* const* d_in, const int* in_sizes, int n_in,
                              void* d_out, int out_size, void* d_ws, size_t ws_size,
                              hipStream_t stream) {
  const float* ee     = (const float*)d_in[0];
  const float* coords = (const float*)d_in[1];
  const float* mask   = (const float*)d_in[2];
  const float* w1     = (const float*)d_in[3];
  const float* rg     = (const float*)d_in[4];
  const float* rbta   = (const float*)d_in[5];
  const float* w2     = (const float*)d_in[6];
  const float* g3     = (const float*)d_in[7];
  const float* b3     = (const float*)d_in[8];
  const float* w3     = (const float*)d_in[9];
  const float* sln_g  = (const float*)d_in[10];
  const float* sln_b  = (const float*)d_in[11];
  const float* eln_g  = (const float*)d_in[17];
  const float* eln_b  = (const float*)d_in[18];
  float* out = (float*)d_out;
  char* ws = (char*)d_ws;

  u16*   wT_s  = (u16*)(ws + 0);           // 512x128 bf16
  u16*   wT_e  = (u16*)(ws + 131072);
  u16*   woT_s = (u16*)(ws + 262144);      // 128x128 bf16
  u16*   woT_e = (u16*)(ws + 294912);
  u16*   ebx0  = (u16*)(ws + 327680);      // exp(bias) frag [4][16][16][64][4] bf16 (512KB)
  u16*   ebxT  = (u16*)(ws + 851968);      // transposed-frame version (512KB)
  float* maskE = (float*)(ws + 1376256);   // transposed mask [256][256] f32 (256KB)
  u16*   zln   = (u16*)(ws + 1638400);     // [65536][128] bf16 (reused as og)
  u16*   Qf    = (u16*)(ws + 18415616);    // frag-tiled
  u16*   Kf    = (u16*)(ws + 35192832);
  u16*   Vf    = (u16*)(ws + 51970048);
  u16*   Gm    = (u16*)(ws + 68747264);    // [65536][128] bf16

  for (int s=0;s<4;s++)
    kconv_t<<<64,256,0,stream>>>((const float*)d_in[12+s], wT_s + s*128*128);
  kconv_t<<<64,256,0,stream>>>((const float*)d_in[16], woT_s);
  for (int s=0;s<4;s++)
    kconv_t<<<64,256,0,stream>>>((const float*)d_in[19+s], wT_e + s*128*128);
  kconv_t<<<64,256,0,stream>>>((const float*)d_in[23], woT_e);

  kprep<<<16384,256,0,stream>>>(ee, coords, w1, rg, rbta, w2, g3, b3, w3, sln_g, sln_b,
                                mask, zln, ebx0, ebxT, maskE);

  // ---- starting pass ----
  kqkvg<<<dim3(512,4),256,0,stream>>>(zln, wT_s, Qf, Kf, Vf, Gm);
  kattn<<<dim3(256,4),256,0,stream>>>(Qf, Kf, Vf, ebx0, mask, zln /*og*/);
  kproj<<<512,256,0,stream>>>(zln /*og*/, Gm, woT_s, ee, out, 0);

  // ---- ending pass (transposed frame) ----
  klnt<<<16384,256,0,stream>>>(out, eln_g, eln_b, zln);
  kqkvg<<<dim3(512,4),256,0,stream>>>(zln, wT_e, Qf, Kf, Vf, Gm);
  kattn<<<dim3(256,4),256,0,stream>>>(Qf, Kf, Vf, ebxT, maskE, zln /*og*/);
  kproj<<<512,256,0,stream>>>(zln /*og*/, Gm, woT_e, out, out, 1);
}